// Round 1
// baseline (682.462 us; speedup 1.0000x reference)
//
#include <hip/hip_runtime.h>

#define Bn 2
#define Cn 64
#define Hn 224
#define Wn 224
#define HWn (Hn*Wn)
#define RCn 8
#define WSn 32
#define OVn 8
#define STRIDEn 24
#define NHn 9
#define NWn 9
#define NTn 1024
#define TKn 64

// fade weight factor for window index i, in-window position p (applies to both axes; NH==NW==9)
__device__ __forceinline__ float edge_w(int i, int p) {
  float w = 1.0f;
  if (i > 0 && p < OVn)            w *= (float)p * (1.0f/7.0f);
  if (i < NHn-1 && p >= WSn-OVn)   w *= (float)(WSn-1-p) * (1.0f/7.0f);
  return w;
}

// sum over windows covering position h of edge_w -> separable cnt
__device__ __forceinline__ float covsum(int h) {
  int ihi = h / STRIDEn; if (ihi > NHn-1) ihi = NHn-1;
  float s = edge_w(ihi, h - STRIDEn*ihi);
  int ilo = ihi - 1;
  if (ilo >= 0) {
    int p = h - STRIDEn*ilo;
    if (p < WSn) s += edge_w(ilo, p);
  }
  return s;
}

__global__ __launch_bounds__(256) void qkv_kernel(
    const float* __restrict__ x,
    const float* __restrict__ Wq, const float* __restrict__ bq,
    const float* __restrict__ Wk, const float* __restrict__ bk,
    const float* __restrict__ Wv, const float* __restrict__ bv,
    float* __restrict__ qb, float* __restrict__ kb, float* __restrict__ vb)
{
  __shared__ float sW[80*64];   // rows 0-7: Wq, 8-15: Wk, 16-79: Wv
  __shared__ float sb[80];
  int tid = threadIdx.x;
  for (int i = tid; i < 8*64; i += 256) { sW[i] = Wq[i]; sW[512 + i] = Wk[i]; }
  for (int i = tid; i < 64*64; i += 256) sW[1024 + i] = Wv[i];
  if (tid < 8)  { sb[tid] = bq[tid]; sb[8 + tid] = bk[tid]; }
  if (tid >= 64 && tid < 128) sb[16 + (tid - 64)] = bv[tid - 64];
  __syncthreads();

  int pix = blockIdx.x * 256 + tid;      // B*H*W = 100352 = 392*256 exactly
  int b  = pix / HWn;
  int hw = pix - b * HWn;
  const float* xp = x + (size_t)b * Cn * HWn + hw;
  float xr[64];
  #pragma unroll
  for (int c = 0; c < 64; ++c) xr[c] = xp[(size_t)c * HWn];

  // q and k (8 outputs each)
  float q8[8], k8[8];
  #pragma unroll
  for (int o = 0; o < 8; ++o) {
    const float4* wrq = (const float4*)(sW + o*64);
    const float4* wrk = (const float4*)(sW + 512 + o*64);
    float sq = sb[o], sk = sb[8+o];
    #pragma unroll
    for (int c4 = 0; c4 < 16; ++c4) {
      float4 wq4 = wrq[c4]; float4 wk4 = wrk[c4];
      sq = fmaf(wq4.x, xr[4*c4+0], sq); sq = fmaf(wq4.y, xr[4*c4+1], sq);
      sq = fmaf(wq4.z, xr[4*c4+2], sq); sq = fmaf(wq4.w, xr[4*c4+3], sq);
      sk = fmaf(wk4.x, xr[4*c4+0], sk); sk = fmaf(wk4.y, xr[4*c4+1], sk);
      sk = fmaf(wk4.z, xr[4*c4+2], sk); sk = fmaf(wk4.w, xr[4*c4+3], sk);
    }
    q8[o] = sq; k8[o] = sk;
  }
  float4* qo = (float4*)(qb + (size_t)pix*8);
  qo[0] = make_float4(q8[0],q8[1],q8[2],q8[3]);
  qo[1] = make_float4(q8[4],q8[5],q8[6],q8[7]);
  float4* ko = (float4*)(kb + (size_t)pix*8);
  ko[0] = make_float4(k8[0],k8[1],k8[2],k8[3]);
  ko[1] = make_float4(k8[4],k8[5],k8[6],k8[7]);

  // v (64 outputs), in groups of 4 to limit registers
  float4* vo = (float4*)(vb + (size_t)pix*64);
  for (int og = 0; og < 16; ++og) {
    float v4[4];
    #pragma unroll
    for (int t = 0; t < 4; ++t) {
      int o = og*4 + t;
      const float4* wr = (const float4*)(sW + 1024 + o*64);
      float s = sb[16+o];
      #pragma unroll
      for (int c4 = 0; c4 < 16; ++c4) {
        float4 w4 = wr[c4];
        s = fmaf(w4.x, xr[4*c4+0], s); s = fmaf(w4.y, xr[4*c4+1], s);
        s = fmaf(w4.z, xr[4*c4+2], s); s = fmaf(w4.w, xr[4*c4+3], s);
      }
      v4[t] = s;
    }
    vo[og] = make_float4(v4[0],v4[1],v4[2],v4[3]);
  }
}

// one block = one window x one 256-query chunk; grid = B*NH*NW*4 = 648
__global__ __launch_bounds__(256) void attn_kernel(
    const float* __restrict__ qb, const float* __restrict__ kb,
    const float* __restrict__ vb, float* __restrict__ outacc)
{
  __shared__ float sK[TKn*8];    // [key][8]
  __shared__ float sV[TKn*64];   // [key][64]

  int bid = blockIdx.x;
  int chunk = bid & 3;
  int win = bid >> 2;
  int b  = win / (NHn*NWn);
  int ij = win - b*(NHn*NWn);
  int wi = ij / NWn;
  int wj = ij - wi*NWn;

  int tid = threadIdx.x;
  int p  = chunk*256 + tid;      // query index in window [0,1024)
  int ph = p >> 5, pw = p & 31;
  int qh = STRIDEn*wi + ph, qw = STRIDEn*wj + pw;
  size_t qpix = ((size_t)b*Hn + qh)*Wn + qw;

  const float4* qp = (const float4*)(qb + qpix*8);
  float4 qv0 = qp[0], qv1 = qp[1];

  float4 accv[16];
  #pragma unroll
  for (int c4 = 0; c4 < 16; ++c4) accv[c4] = make_float4(0.f,0.f,0.f,0.f);
  float l = 0.f;

  for (int kt = 0; kt < NTn/TKn; ++kt) {   // 16 tiles of 64 keys
    __syncthreads();
    // stage V: 64 keys * 16 float4 = 1024 float4
    for (int n = tid; n < TKn*16; n += 256) {
      int key = kt*TKn + (n >> 4);
      int kh = STRIDEn*wi + (key >> 5), kw = STRIDEn*wj + (key & 31);
      size_t kpix = ((size_t)b*Hn + kh)*Wn + kw;
      ((float4*)sV)[n] = ((const float4*)(vb + kpix*64))[n & 15];
    }
    // stage K: 64 keys * 2 float4 = 128 float4
    if (tid < TKn*2) {
      int key = kt*TKn + (tid >> 1);
      int kh = STRIDEn*wi + (key >> 5), kw = STRIDEn*wj + (key & 31);
      size_t kpix = ((size_t)b*Hn + kh)*Wn + kw;
      ((float4*)sK)[tid] = ((const float4*)(kb + kpix*8))[tid & 1];
    }
    __syncthreads();

    #pragma unroll 2
    for (int j = 0; j < TKn; ++j) {
      const float4* kr = (const float4*)(sK + j*8);
      float4 ka = kr[0], kb4 = kr[1];
      float s = qv0.x*ka.x + qv0.y*ka.y + qv0.z*ka.z + qv0.w*ka.w
              + qv1.x*kb4.x + qv1.y*kb4.y + qv1.z*kb4.z + qv1.w*kb4.w;
      float pe = __expf(s * 0.03125f);   // /sqrt(1024); |s/32| < ~0.5, no max needed
      l += pe;
      const float4* vr = (const float4*)(sV + j*64);
      #pragma unroll
      for (int c4 = 0; c4 < 16; ++c4) {
        float4 v = vr[c4];
        accv[c4].x = fmaf(pe, v.x, accv[c4].x);
        accv[c4].y = fmaf(pe, v.y, accv[c4].y);
        accv[c4].z = fmaf(pe, v.z, accv[c4].z);
        accv[c4].w = fmaf(pe, v.w, accv[c4].w);
      }
    }
  }

  float wgt = edge_w(wi, ph) * edge_w(wj, pw);
  float sc = wgt / l;
  float* op = outacc + (size_t)b*Cn*HWn + (size_t)qh*Wn + qw;
  #pragma unroll
  for (int c4 = 0; c4 < 16; ++c4) {
    atomicAdd(op + (size_t)(4*c4+0)*HWn, accv[c4].x*sc);
    atomicAdd(op + (size_t)(4*c4+1)*HWn, accv[c4].y*sc);
    atomicAdd(op + (size_t)(4*c4+2)*HWn, accv[c4].z*sc);
    atomicAdd(op + (size_t)(4*c4+3)*HWn, accv[c4].w*sc);
  }
}

// in-place: out = x + gamma * out/(cnt+1e-8); one thread = one float4
__global__ __launch_bounds__(256) void final_kernel(
    const float* __restrict__ x, const float* __restrict__ gamma,
    float* __restrict__ out)
{
  int idx4 = blockIdx.x * 256 + threadIdx.x;   // < B*C*H*W/4 = 1605632
  int w4    = idx4 % (Wn/4);
  int rowid = idx4 / (Wn/4);
  int h = rowid % Hn;
  float g = gamma[0];
  float rs = covsum(h);
  int w0 = w4*4;
  float c0 = rs * covsum(w0+0) + 1e-8f;
  float c1 = rs * covsum(w0+1) + 1e-8f;
  float c2 = rs * covsum(w0+2) + 1e-8f;
  float c3 = rs * covsum(w0+3) + 1e-8f;
  float4 xv = ((const float4*)x)[idx4];
  float4 av = ((float4*)out)[idx4];
  float4 r;
  r.x = xv.x + g * av.x / c0;
  r.y = xv.y + g * av.y / c1;
  r.z = xv.z + g * av.z / c2;
  r.w = xv.w + g * av.w / c3;
  ((float4*)out)[idx4] = r;
}

extern "C" void kernel_launch(void* const* d_in, const int* in_sizes, int n_in,
                              void* d_out, int out_size, void* d_ws, size_t ws_size,
                              hipStream_t stream) {
  const float* x     = (const float*)d_in[0];
  const float* Wq    = (const float*)d_in[1];
  const float* bq    = (const float*)d_in[2];
  const float* Wk    = (const float*)d_in[3];
  const float* bk    = (const float*)d_in[4];
  const float* Wv    = (const float*)d_in[5];
  const float* bv    = (const float*)d_in[6];
  const float* gamma = (const float*)d_in[7];
  float* out = (float*)d_out;

  float* qb = (float*)d_ws;                       // B*H*W*8  floats
  float* kb = qb + (size_t)Bn*HWn*8;              // B*H*W*8
  float* vb = kb + (size_t)Bn*HWn*8;              // B*H*W*64

  hipMemsetAsync(d_out, 0, (size_t)out_size * sizeof(float), stream);
  qkv_kernel<<<(Bn*HWn)/256, 256, 0, stream>>>(x, Wq, bq, Wk, bk, Wv, bv, qb, kb, vb);
  attn_kernel<<<Bn*NHn*NWn*4, 256, 0, stream>>>(qb, kb, vb, out);
  final_kernel<<<(Bn*Cn*HWn/4)/256, 256, 0, stream>>>(x, gamma, out);
}

// Round 3
// 177.145 us; speedup vs baseline: 3.8526x; 3.8526x over previous
//
#include <hip/hip_runtime.h>

#define Bn 2
#define Cn 64
#define Hn 224
#define Wn 224
#define HWn (Hn*Wn)
#define WSn 32
#define OVn 8
#define STRIDEn 24
#define NHn 9
#define NWn 9
#define QSCALE (1.44269504088896f/32.0f)

typedef __bf16 bf16x8 __attribute__((ext_vector_type(8)));
typedef float f32x16 __attribute__((ext_vector_type(16)));
typedef unsigned int uint4v __attribute__((ext_vector_type(4)));

union PackU { uint4v u; bf16x8 h; };
union BfPair { __bf16 h[2]; unsigned u; };

__device__ __forceinline__ float fast_exp2(float x) {
#if __has_builtin(__builtin_amdgcn_exp2f)
  return __builtin_amdgcn_exp2f(x);
#else
  return exp2f(x);
#endif
}

// fade weight factor for window index i, in-window position p
__device__ __forceinline__ float edge_w(int i, int p) {
  float w = 1.0f;
  if (i > 0 && p < OVn)            w *= (float)p * (1.0f/7.0f);
  if (i < NHn-1 && p >= WSn-OVn)   w *= (float)(WSn-1-p) * (1.0f/7.0f);
  return w;
}

// separable coverage sum
__device__ __forceinline__ float covsum(int h) {
  int ihi = h / STRIDEn; if (ihi > NHn-1) ihi = NHn-1;
  float s = edge_w(ihi, h - STRIDEn*ihi);
  int ilo = ihi - 1;
  if (ilo >= 0) {
    int p = h - STRIDEn*ilo;
    if (p < WSn) s += edge_w(ilo, p);
  }
  return s;
}

// ---------------- QKV projection: fp32 in, bf16 out ----------------
// qb: [pix][8] bf16, PRE-SCALED by log2e/32.  kb: [pix][8] bf16.
// vbt: [b][c][h][w] bf16 (channel-major, for PV B-fragment loads).
__global__ __launch_bounds__(256) void qkv_kernel(
    const float* __restrict__ x,
    const float* __restrict__ Wq, const float* __restrict__ bq,
    const float* __restrict__ Wk, const float* __restrict__ bk,
    const float* __restrict__ Wv, const float* __restrict__ bv,
    __bf16* __restrict__ qb, __bf16* __restrict__ kb, __bf16* __restrict__ vbt)
{
  __shared__ float sW[80*64];   // rows 0-7: Wq, 8-15: Wk, 16-79: Wv
  __shared__ float sb[80];
  int tid = threadIdx.x;
  for (int i = tid; i < 8*64; i += 256) { sW[i] = Wq[i]; sW[512 + i] = Wk[i]; }
  for (int i = tid; i < 64*64; i += 256) sW[1024 + i] = Wv[i];
  if (tid < 8)  { sb[tid] = bq[tid]; sb[8 + tid] = bk[tid]; }
  if (tid >= 64 && tid < 128) sb[16 + (tid - 64)] = bv[tid - 64];
  __syncthreads();

  int pix = blockIdx.x * 256 + tid;      // B*H*W = 100352 = 392*256
  int b  = pix / HWn;
  int hw = pix - b * HWn;
  const float* xp = x + (size_t)b * Cn * HWn + hw;
  float xr[64];
  #pragma unroll
  for (int c = 0; c < 64; ++c) xr[c] = xp[(size_t)c * HWn];

  float q8[8], k8[8];
  #pragma unroll
  for (int o = 0; o < 8; ++o) {
    const float4* wrq = (const float4*)(sW + o*64);
    const float4* wrk = (const float4*)(sW + 512 + o*64);
    float sq = sb[o], sk = sb[8+o];
    #pragma unroll
    for (int c4 = 0; c4 < 16; ++c4) {
      float4 wq4 = wrq[c4]; float4 wk4 = wrk[c4];
      sq = fmaf(wq4.x, xr[4*c4+0], sq); sq = fmaf(wq4.y, xr[4*c4+1], sq);
      sq = fmaf(wq4.z, xr[4*c4+2], sq); sq = fmaf(wq4.w, xr[4*c4+3], sq);
      sk = fmaf(wk4.x, xr[4*c4+0], sk); sk = fmaf(wk4.y, xr[4*c4+1], sk);
      sk = fmaf(wk4.z, xr[4*c4+2], sk); sk = fmaf(wk4.w, xr[4*c4+3], sk);
    }
    q8[o] = sq; k8[o] = sk;
  }
  PackU qo, ko;
  #pragma unroll
  for (int o = 0; o < 8; ++o) {
    qo.h[o] = (__bf16)(q8[o] * QSCALE);
    ko.h[o] = (__bf16)k8[o];
  }
  *(uint4v*)(qb + (size_t)pix*8) = qo.u;
  *(uint4v*)(kb + (size_t)pix*8) = ko.u;

  __bf16* vo = vbt + (size_t)b*Cn*HWn + hw;
  for (int og = 0; og < 16; ++og) {
    #pragma unroll
    for (int t = 0; t < 4; ++t) {
      int o = og*4 + t;
      const float4* wr = (const float4*)(sW + 1024 + o*64);
      float s = sb[16+o];
      #pragma unroll
      for (int c4 = 0; c4 < 16; ++c4) {
        float4 w4 = wr[c4];
        s = fmaf(w4.x, xr[4*c4+0], s); s = fmaf(w4.y, xr[4*c4+1], s);
        s = fmaf(w4.z, xr[4*c4+2], s); s = fmaf(w4.w, xr[4*c4+3], s);
      }
      vo[(size_t)o * HWn] = (__bf16)s;
    }
  }
}

// ---------------- MFMA flash attention ----------------
// One wave (64 threads) = one window row (32 queries). 5184 blocks.
__global__ __launch_bounds__(64, 4) void attn_kernel(
    const __bf16* __restrict__ qb, const __bf16* __restrict__ kb,
    const __bf16* __restrict__ vbt, float* __restrict__ outacc)
{
  __shared__ float T[32][33];
  // XCD swizzle: consecutive bidm (same window) on the same XCD. 5184 = 8*648.
  int bidm = (blockIdx.x & 7) * 648 + (blockIdx.x >> 3);
  int win = bidm >> 5;
  int ph  = bidm & 31;
  int b  = win / (NHn*NWn);
  int ij = win - b*(NHn*NWn);
  int wi = ij / NWn;
  int wj = ij - wi*NWn;
  int lane = threadIdx.x;
  int lo = lane & 31, hi = lane >> 5;
  int h0 = wi*STRIDEn, w0 = wj*STRIDEn;

  // Q fragment (B operand): lane holds Q[query=lo][ch=8*hi+j]; hi lanes = 0 (ch 8..15 pad)
  bf16x8 qf = {};
  if (hi == 0)
    qf = *(const bf16x8*)(qb + ((size_t)(b*Hn + h0 + ph)*Wn + w0 + lo) * 8);

  const __bf16* kbase = kb + ((size_t)(b*Hn + h0)*Wn + w0 + lo) * 8;               // + kt*Wn*8
  const __bf16* vbase = vbt + (size_t)(b*Cn + lo)*HWn + (size_t)h0*Wn + w0 + 8*hi; // + kt*Wn + 16s (+32*HWn)

  f32x16 acc0 = {}, acc1 = {};
  float lsum = 0.f;

  #pragma unroll 2
  for (int kt = 0; kt < 32; ++kt) {
    // K fragment (A operand): lane holds K[key=lo][ch=8*hi+j]; hi lanes zero-padded
    bf16x8 kf = {};
    if (hi == 0)
      kf = *(const bf16x8*)(kbase + (size_t)kt*Wn*8);

    // V fragments (B operand of PV): lane holds V[key=16s+8hi+j][ch=lo (+32)]
    const __bf16* vk = vbase + (size_t)kt*Wn;
    bf16x8 vf00 = *(const bf16x8*)(vk);
    bf16x8 vf01 = *(const bf16x8*)(vk + (size_t)32*HWn);
    bf16x8 vf10 = *(const bf16x8*)(vk + 16);
    bf16x8 vf11 = *(const bf16x8*)(vk + 16 + (size_t)32*HWn);

    // S[key][query]: key = (r&3)+8*(r>>2)+4*hi, query = lo. Scores already log2-domain.
    f32x16 s = __builtin_amdgcn_mfma_f32_32x32x16_bf16(kf, qf, (f32x16){}, 0, 0, 0);

    // exp2 + pack pairs to bf16 (compiler-visible; clamp makes overflow impossible)
    unsigned w[8];
    #pragma unroll
    for (int d = 0; d < 8; ++d) {
      float a  = fast_exp2(fminf(s[2*d],   60.0f));
      float b2 = fast_exp2(fminf(s[2*d+1], 60.0f));
      lsum += a + b2;
      BfPair pr; pr.h[0] = (__bf16)a; pr.h[1] = (__bf16)b2;
      w[d] = pr.u;
    }
    // lane (lo,hi) word contents (key pairs):
    //   w0={4hi+0,1} w1={4hi+2,3} w2={8+4hi+0,1} w3={8+4hi+2,3}
    //   w4={16+4hi+0,1} w5={16+4hi+2,3} w6={24+4hi+0,1} w7={24+4hi+2,3}
    unsigned pw[8];
    #pragma unroll
    for (int d = 0; d < 8; ++d) pw[d] = __shfl_xor(w[d], 32);

    // PV A-operand needs keys 8*hi+{0..7} (pa0: keys 0-15) / 16+8*hi+{0..7} (pa1)
    PackU pa0, pa1;
    pa0.u = (uint4v){ hi ? pw[2] : w[0],  hi ? pw[3] : w[1],
                      hi ? w[2]  : pw[0], hi ? w[3]  : pw[1] };
    pa1.u = (uint4v){ hi ? pw[6] : w[4],  hi ? pw[7] : w[5],
                      hi ? w[6]  : pw[4], hi ? w[7]  : pw[5] };

    acc0 = __builtin_amdgcn_mfma_f32_32x32x16_bf16(pa0.h, vf00, acc0, 0, 0, 0);
    acc1 = __builtin_amdgcn_mfma_f32_32x32x16_bf16(pa0.h, vf01, acc1, 0, 0, 0);
    acc0 = __builtin_amdgcn_mfma_f32_32x32x16_bf16(pa1.h, vf10, acc0, 0, 0, 0);
    acc1 = __builtin_amdgcn_mfma_f32_32x32x16_bf16(pa1.h, vf11, acc1, 0, 0, 0);
  }

  // denominator: partner half holds the other 16 keys of every tile
  lsum += __shfl_xor(lsum, 32);
  float sc = edge_w(wi, ph) * edge_w(wj, lo) / lsum;   // lane's query = lo
  int qh = h0 + ph;
  float* ob = outacc + (size_t)b*Cn*HWn + (size_t)qh*Wn + w0;

  // acc layout: D[query=(r&3)+8*(r>>2)+4*hi][ch=lo]; transpose via LDS so
  // atomics are coalesced along w (query), then ch strided.
  #pragma unroll
  for (int r = 0; r < 16; ++r) T[(r&3) + 8*(r>>2) + 4*hi][lo] = acc0[r];
  __syncthreads();
  #pragma unroll
  for (int rr = 0; rr < 16; ++rr)
    atomicAdd(ob + (size_t)(2*rr + hi)*HWn + lo, T[lo][2*rr + hi] * sc);
  __syncthreads();
  #pragma unroll
  for (int r = 0; r < 16; ++r) T[(r&3) + 8*(r>>2) + 4*hi][lo] = acc1[r];
  __syncthreads();
  #pragma unroll
  for (int rr = 0; rr < 16; ++rr)
    atomicAdd(ob + (size_t)(32 + 2*rr + hi)*HWn + lo, T[lo][2*rr + hi] * sc);
}

// ---------------- final blend: out = x + gamma * acc/(cnt+1e-8) ----------------
__global__ __launch_bounds__(256) void final_kernel(
    const float* __restrict__ x, const float* __restrict__ gamma,
    float* __restrict__ out)
{
  int idx4 = blockIdx.x * 256 + threadIdx.x;
  int w4    = idx4 % (Wn/4);
  int rowid = idx4 / (Wn/4);
  int h = rowid % Hn;
  float g = gamma[0];
  float rs = covsum(h);
  int w0 = w4*4;
  float c0 = rs * covsum(w0+0) + 1e-8f;
  float c1 = rs * covsum(w0+1) + 1e-8f;
  float c2 = rs * covsum(w0+2) + 1e-8f;
  float c3 = rs * covsum(w0+3) + 1e-8f;
  float4 xv = ((const float4*)x)[idx4];
  float4 av = ((float4*)out)[idx4];
  float4 r;
  r.x = xv.x + g * av.x / c0;
  r.y = xv.y + g * av.y / c1;
  r.z = xv.z + g * av.z / c2;
  r.w = xv.w + g * av.w / c3;
  ((float4*)out)[idx4] = r;
}

extern "C" void kernel_launch(void* const* d_in, const int* in_sizes, int n_in,
                              void* d_out, int out_size, void* d_ws, size_t ws_size,
                              hipStream_t stream) {
  const float* x     = (const float*)d_in[0];
  const float* Wq    = (const float*)d_in[1];
  const float* bq    = (const float*)d_in[2];
  const float* Wk    = (const float*)d_in[3];
  const float* bk    = (const float*)d_in[4];
  const float* Wv    = (const float*)d_in[5];
  const float* bv    = (const float*)d_in[6];
  const float* gamma = (const float*)d_in[7];
  float* out = (float*)d_out;

  __bf16* qb  = (__bf16*)d_ws;                       // B*H*W*8
  __bf16* kb  = qb + (size_t)Bn*HWn*8;               // B*H*W*8
  __bf16* vbt = kb + (size_t)Bn*HWn*8;               // B*C*H*W (channel-major)

  hipMemsetAsync(d_out, 0, (size_t)out_size * sizeof(float), stream);
  qkv_kernel<<<(Bn*HWn)/256, 256, 0, stream>>>(x, Wq, bq, Wk, bk, Wv, bv, qb, kb, vbt);
  attn_kernel<<<Bn*NHn*NWn*32, 64, 0, stream>>>(qb, kb, vbt, out);
  final_kernel<<<(Bn*Cn*HWn/4)/256, 256, 0, stream>>>(x, gamma, out);
}